// Round 8
// baseline (377.458 us; speedup 1.0000x reference)
//
#include <hip/hip_runtime.h>
#include <hip/hip_bf16.h>
#include <math.h>

// B=2 QL=512 KL=8192 D=1024 H=8 HD=128
typedef __attribute__((ext_vector_type(4))) float fx4;
typedef __attribute__((ext_vector_type(4))) short sx4;
typedef __attribute__((ext_vector_type(8))) short sx8;
typedef unsigned long long u64;

#define MFMA16(a, b, c) __builtin_amdgcn_mfma_f32_16x16x16bf16_1k(a, b, c, 0, 0, 0)
#define MFMA32(a, b, c) __builtin_amdgcn_mfma_f32_16x16x32_bf16(a, b, c, 0, 0, 0)

__device__ __forceinline__ unsigned short f2bf(float f) {
  unsigned int u = __float_as_uint(f);
  return (unsigned short)((u + 0x7fffu + ((u >> 16) & 1u)) >> 16);  // RNE
}

// packed f32x2 -> bf16x2 (RNE)
__device__ __forceinline__ unsigned cvtpk(float lo, float hi) {
  unsigned r;
  asm("v_cvt_pk_bf16_f32 %0, %1, %2" : "=v"(r) : "v"(lo), "v"(hi));
  return r;
}

// async global->LDS, 16B per lane; LDS dest is wave-uniform base + lane*16
typedef const __attribute__((address_space(1))) char* gc1p;
typedef __attribute__((address_space(3))) char* lc3p;
__device__ __forceinline__ void glds16(const void* g, const void* lds_uniform) {
  gc1p gp = (gc1p)(unsigned long long)(uintptr_t)g;
  lc3p lp = (lc3p)(unsigned)__builtin_amdgcn_readfirstlane((int)(unsigned)(uintptr_t)lds_uniform);
  __builtin_amdgcn_global_load_lds(gp, lp, 16, 0, 0);
}

// ---------------- prep (slim): weights f32->bf16 only ------------------------
__global__ __launch_bounds__(256) void k_prep(
    const float* __restrict__ Wq, const float* __restrict__ Wk,
    const float* __restrict__ Wv, const float* __restrict__ Wf, short* cwq,
    short* cwk, short* cwv, short* cwf) {
  const int bx = blockIdx.x;
  const int t = threadIdx.x;
  const int seg = bx >> 6;
  const float* s = seg == 0 ? Wq : seg == 1 ? Wk : seg == 2 ? Wv : Wf;
  short* d = seg == 0 ? cwq : seg == 1 ? cwk : seg == 2 ? cwv : cwf;
  const size_t base = (size_t)(bx & 63) * 16384;
#pragma unroll
  for (int it = 0; it < 4; it++) {
    const size_t i = base + (size_t)it * 4096 + (size_t)t * 16;
    const fx4 a0 = *(const fx4*)(s + i);
    const fx4 a1 = *(const fx4*)(s + i + 4);
    const fx4 a2 = *(const fx4*)(s + i + 8);
    const fx4 a3 = *(const fx4*)(s + i + 12);
    sx8 o0, o1;
    o0[0] = (short)f2bf(a0[0]); o0[1] = (short)f2bf(a0[1]);
    o0[2] = (short)f2bf(a0[2]); o0[3] = (short)f2bf(a0[3]);
    o0[4] = (short)f2bf(a1[0]); o0[5] = (short)f2bf(a1[1]);
    o0[6] = (short)f2bf(a1[2]); o0[7] = (short)f2bf(a1[3]);
    o1[0] = (short)f2bf(a2[0]); o1[1] = (short)f2bf(a2[1]);
    o1[2] = (short)f2bf(a2[2]); o1[3] = (short)f2bf(a2[3]);
    o1[4] = (short)f2bf(a3[0]); o1[5] = (short)f2bf(a3[1]);
    o1[6] = (short)f2bf(a3[2]); o1[7] = (short)f2bf(a3[3]);
    *(sx8*)(d + i) = o0;
    *(sx8*)(d + i + 8) = o1;
  }
}

// ---------------- 256x256-tile 8-wave AF32 GEMM ------------------------------
// C = alpha*(A_f32[M,1024] @ B_bf16[1024,1024]^T + bias). 512 threads, 8 waves
// (2M x 4N, per-wave 128x64, acc 8x4), BK=64, LDS 128KB (A+B dbuf).
// Schedule per iter t: CVT_A(t) (implicit vmcnt drains A(t)+B(t), both with a
// FULL iteration of flight) -> issue B(t+1)+A(t+1) -> lgkm barrier ->
// COMPUTE(t) [2.5 kcy of MFMA per SIMD hides the stage cost] -> lgkm barrier.
// No vmcnt(0)-at-barrier anywhere: drains only happen after full-iter cover.
// mode 0: bf16 row-major C (alpha). mode 2: bf16 V^T with 8B-half swap.
__device__ __forceinline__ void gemm256_body(
    short* sA, short* sB, const float* __restrict__ Af,
    const short* __restrict__ Bw, const float* __restrict__ bias,
    void* __restrict__ Cptr, int M, float alpha, int mode, int bx) {
  constexpr int K = 1024;
  const int tid = threadIdx.x;  // 0..511
  const int lane = tid & 63;
  const int w = tid >> 6;  // 0..7
  const int quad = lane >> 4;
  const int l16 = lane & 15;
  const int x7 = l16 & 7;
  int m0, n0;
  if (M >= 8192) {  // 64 strips x 4 n; 4 n-siblings of a strip share one XCD
    const int xcd = bx & 7, idx = bx >> 3;
    m0 = ((idx >> 2) * 8 + xcd) << 8;
    n0 = (idx & 3) << 8;
  } else {
    m0 = (bx >> 2) << 8;
    n0 = (bx & 3) << 8;
  }
  const int wm = (w >> 2) << 7;  // 0 or 128
  const int wn = (w & 3) << 6;   // 0,64,128,192
  const fx4 fzero = {0.f, 0.f, 0.f, 0.f};
  fx4 acc[8][4];
#pragma unroll
  for (int i = 0; i < 8; i++)
#pragma unroll
    for (int j = 0; j < 4; j++) acc[i][j] = fzero;

  const int arow = tid >> 3;               // A: row within 64-row group
  const int acb = tid & 7;                 // A: 32B chunk
  const int brow = w * 8 + (lane >> 3);    // B: row within 64-row group
  const int bcb = lane & 7;                // B: 16B chunk
  fx4 ra[4][2];

  // ---- prologue: issue B(0) then A(0) (B older -> drained by A(0)'s wait) --
#pragma unroll
  for (int j = 0; j < 4; j++) {
    const int row = j * 64 + brow;
    const int cb = bcb ^ (row & 7);
    glds16(Bw + (size_t)(n0 + row) * K + cb * 8, &sB[(j * 64 + w * 8) * 64]);
  }
#pragma unroll
  for (int j = 0; j < 4; j++) {
    const int row = j * 64 + arow;
    const int cb = acb ^ (row & 7);
    const float* src = Af + (size_t)(m0 + row) * K + cb * 8;
    ra[j][0] = *(const fx4*)src;
    ra[j][1] = *(const fx4*)(src + 4);
  }

  for (int t = 0; t < 16; ++t) {
    const int boff = (t & 1) << 14;  // *16384 shorts
    const int nboff = boff ^ 16384;
    // CVT_A(t): compiler-inserted vmcnt wait drains A(t) (+older B(t)) — both
    // have had a full iteration in flight. Writes pre-swizzled linear slots.
#pragma unroll
    for (int j = 0; j < 4; j++) {
      sx8 o;
      unsigned* ou = (unsigned*)&o;
      ou[0] = cvtpk(ra[j][0][0], ra[j][0][1]);
      ou[1] = cvtpk(ra[j][0][2], ra[j][0][3]);
      ou[2] = cvtpk(ra[j][1][0], ra[j][1][1]);
      ou[3] = cvtpk(ra[j][1][2], ra[j][1][3]);
      *(sx8*)(&sA[boff + j * 4096 + tid * 8]) = o;
    }
    if (t < 15) {  // stage tile t+1: flies across barrier + COMPUTE + barrier
#pragma unroll
      for (int j = 0; j < 4; j++) {
        const int row = j * 64 + brow;
        const int cb = bcb ^ (row & 7);
        glds16(Bw + (size_t)(n0 + row) * K + (t + 1) * 64 + cb * 8,
               &sB[nboff + (j * 64 + w * 8) * 64]);
      }
#pragma unroll
      for (int j = 0; j < 4; j++) {
        const int row = j * 64 + arow;
        const int cb = acb ^ (row & 7);
        const float* src = Af + (size_t)(m0 + row) * K + (t + 1) * 64 + cb * 8;
        ra[j][0] = *(const fx4*)src;
        ra[j][1] = *(const fx4*)(src + 4);
      }
    }
    asm volatile("s_waitcnt lgkmcnt(0)\n\ts_barrier" ::: "memory");
    // COMPUTE(t): 64 MFMA/wave — ~2.5 kcy matrix-pipe per SIMD per window
    const short* pA = sA + boff;
    const short* pB = sB + boff;
#pragma unroll
    for (int kc = 0; kc < 2; kc++) {
      const int cbp = ((kc * 4 + quad) ^ x7) * 8;
      sx8 fa[8], fb[4];
#pragma unroll
      for (int i = 0; i < 8; i++)
        fa[i] = *(const sx8*)(&pA[(wm + i * 16 + l16) * 64 + cbp]);
#pragma unroll
      for (int i = 0; i < 4; i++)
        fb[i] = *(const sx8*)(&pB[(wn + i * 16 + l16) * 64 + cbp]);
#pragma unroll
      for (int mi = 0; mi < 8; mi++)
#pragma unroll
        for (int ni = 0; ni < 4; ni++)
          acc[mi][ni] = MFMA32(fa[mi], fb[ni], acc[mi][ni]);
    }
    asm volatile("s_waitcnt lgkmcnt(0)\n\ts_barrier" ::: "memory");
  }
  // epilogue: C/D layout col=lane&15, row=quad*4+reg
#pragma unroll
  for (int ni = 0; ni < 4; ni++) {
    const int col = n0 + wn + ni * 16 + l16;
    const float bval = bias[col];
    if (mode == 2) {
#pragma unroll
      for (int mi = 0; mi < 8; mi++) {
        const int rowb = m0 + wm + mi * 16 + quad * 4;
        const int bb = rowb >> 13;
        const int kl = (rowb & 8191) ^ ((col & 8) ? 4 : 0);
        sx4 pkv;
#pragma unroll
        for (int r = 0; r < 4; r++) pkv[r] = (short)f2bf(acc[mi][ni][r] + bval);
        *(sx4*)((unsigned short*)Cptr + ((size_t)bb * 1024 + col) * 8192 + kl) = pkv;
      }
    } else {
#pragma unroll
      for (int mi = 0; mi < 8; mi++)
#pragma unroll
        for (int r = 0; r < 4; r++) {
          const int row = m0 + wm + mi * 16 + quad * 4 + r;
          const float v = (acc[mi][ni][r] + bval) * alpha;
          ((unsigned short*)Cptr)[(size_t)row * 1024 + col] = f2bf(v);
        }
    }
  }
}

// ---------------- merged projections + mask pack (512 threads) ---------------
// grid 2576: [0,256) K-proj, [256,512) V-proj, [512,528) Q-proj,
// [528,2576) mask pack (4 rows/block, threads 256..511 idle).
__global__ __launch_bounds__(512, 2) void k_proj(
    const float* __restrict__ ink, const short* __restrict__ cwk,
    const float* __restrict__ bk, short* __restrict__ Kp,
    const float* __restrict__ inv, const short* __restrict__ cwv,
    const float* __restrict__ bv, short* __restrict__ Vt,
    const float* __restrict__ inq, const short* __restrict__ cwq,
    const float* __restrict__ bq, short* __restrict__ Qp, float alpha_q,
    const int* __restrict__ mask, u64* __restrict__ mb) {
  __shared__ __align__(16) short smem[65536];  // 128 KB
  const int bx = blockIdx.x;
  if (bx >= 528) {  // mask pack
    unsigned char(*nib)[256] = (unsigned char(*)[256])smem;
    const int t = threadIdx.x;
    const int mrow0 = (bx - 528) * 4;
    if (t < 256) {
#pragma unroll
      for (int j = 0; j < 4; j++) {
        const int4 m = *(const int4*)(mask + (size_t)(mrow0 + j) * 1024 + t * 4);
        nib[j][t] = (unsigned char)((m.x != 0) | ((m.y != 0) << 1) |
                                    ((m.z != 0) << 2) | ((m.w != 0) << 3));
      }
    }
    __syncthreads();
    if (t < 64) {
      const int j = t >> 4, i = t & 15;
      u64 wv = 0;
#pragma unroll
      for (int k = 0; k < 16; k++)
        wv |= (u64)(nib[j][i * 16 + k] & 0xF) << (4 * k);
      mb[(size_t)(mrow0 + j) * 16 + i] = wv;
    }
    return;
  }
  if (bx < 256)
    gemm256_body(smem, smem + 32768, ink, cwk, bk, Kp, 16384, 1.f, 0, bx);
  else if (bx < 512)
    gemm256_body(smem, smem + 32768, inv, cwv, bv, Vt, 16384, 1.f, 2, bx - 256);
  else
    gemm256_body(smem, smem + 32768, inq, cwq, bq, Qp, 1024, alpha_q, 0,
                 bx - 512);
}

// ---------------- bf16-A GEMM body (dbuf) for out-projection -----------------
__device__ __forceinline__ void gemm_out_body(short* sA, short* sB,
                                              const short* __restrict__ A,
                                              const short* __restrict__ Bw,
                                              const float* __restrict__ bias,
                                              float* __restrict__ Cptr, int N,
                                              int K, int bx) {
  constexpr int MT = 64;
  const int tid = threadIdx.x;
  const int lane = tid & 63;
  const int w = tid >> 6;
  const int quad = lane >> 4;
  const int l16 = lane & 15;
  const int x7 = l16 & 7;
  const int ntile = N >> 7;
  const int n0 = (bx % ntile) << 7;
  const int m0 = (bx / ntile) * MT;
  constexpr int NI = 2;
  const int wm = 0;
  const int wn = w << 5;
  const fx4 fzero = {0.f, 0.f, 0.f, 0.f};
  fx4 acc[4][NI];
#pragma unroll
  for (int i = 0; i < 4; i++)
#pragma unroll
    for (int j = 0; j < NI; j++) acc[i][j] = fzero;
  const int srow = lane >> 3;
  const int scb = lane & 7;

#pragma unroll
  for (int j = 0; j < 2; j++) {
    const int rbase = j * 32 + w * 8;
    const int row = rbase + srow;
    const int cb = scb ^ (row & 7);
    glds16(A + (size_t)(m0 + row) * K + cb * 8, &sA[rbase * 64]);
  }
#pragma unroll
  for (int j = 0; j < 4; j++) {
    const int row = w * 32 + j * 8 + srow;
    const int cb = scb ^ (row & 7);
    glds16(Bw + (size_t)(n0 + row) * K + cb * 8, &sB[(w * 32 + j * 8) * 64]);
  }
  __syncthreads();

  int buf = 0;
  for (int k0 = 0; k0 < K; k0 += 64) {
    const int nb = buf ^ 1;
    if (k0 + 64 < K) {
#pragma unroll
      for (int j = 0; j < 4; j++) {
        const int row = w * 32 + j * 8 + srow;
        const int cb = scb ^ (row & 7);
        glds16(Bw + (size_t)(n0 + row) * K + (k0 + 64) + cb * 8,
               &sB[nb * 8192 + (w * 32 + j * 8) * 64]);
      }
#pragma unroll
      for (int j = 0; j < 2; j++) {
        const int rbase = j * 32 + w * 8;
        const int row = rbase + srow;
        const int cb = scb ^ (row & 7);
        glds16(A + (size_t)(m0 + row) * K + (k0 + 64) + cb * 8,
               &sA[nb * 8192 + rbase * 64]);
      }
    }
    const short* pA = sA + buf * 8192;
    const short* pB = sB + buf * 8192;
#pragma unroll
    for (int kc = 0; kc < 2; kc++) {
      const int cbp = ((kc * 4 + quad) ^ x7) * 8;
      sx8 fa[4], fb[NI];
#pragma unroll
      for (int i = 0; i < 4; i++)
        fa[i] = *(const sx8*)(&pA[(wm + i * 16 + l16) * 64 + cbp]);
#pragma unroll
      for (int i = 0; i < NI; i++)
        fb[i] = *(const sx8*)(&pB[(wn + i * 16 + l16) * 64 + cbp]);
#pragma unroll
      for (int mi = 0; mi < 4; mi++)
#pragma unroll
        for (int ni = 0; ni < NI; ni++)
          acc[mi][ni] = MFMA32(fa[mi], fb[ni], acc[mi][ni]);
    }
    __syncthreads();
    buf = nb;
  }
#pragma unroll
  for (int ni = 0; ni < NI; ni++) {
    const int col = n0 + wn + ni * 16 + l16;
    const float bval = bias[col];
#pragma unroll
    for (int mi = 0; mi < 4; mi++)
#pragma unroll
      for (int r = 0; r < 4; r++) {
        const int row = m0 + wm + mi * 16 + quad * 4 + r;
        Cptr[(size_t)row * N + col] = acc[mi][ni][r] + bval;
      }
  }
}

// out-projection (A = bf16 summed): grid 128
__global__ __launch_bounds__(256) void k_gemm_out(const short* __restrict__ summed,
                                                  const short* __restrict__ cwf,
                                                  const float* __restrict__ bf,
                                                  float* __restrict__ out) {
  __shared__ __align__(16) short smem[32768];
  gemm_out_body(smem, smem + 16384, summed, cwf, bf, out, 1024, 1024,
                blockIdx.x);
}

// ---------------- flash attention (round-5 version: 2-barrier, 32KB, 4 blk/CU)
__global__ __launch_bounds__(256, 4) void k_attn(const short* __restrict__ Qp,
                                                 const short* __restrict__ Kp,
                                                 const short* __restrict__ Vt,
                                                 const u64* __restrict__ mb,
                                                 float* __restrict__ ml,
                                                 float* __restrict__ Op) {
  __shared__ __align__(16) short sK[8192];  // 64 keys x 128 d (swizzled)
  __shared__ __align__(16) short sV[8192];  // 128 d x 64 keys (swizzled)
  const int x = blockIdx.x;
  const int gl = x & 7;
  const int qt = (x >> 3) & 7;
  const int gh = x >> 6;
  const int g = gh * 8 + gl;  // 0..127
  const int s = g & 7;
  const int h = (g >> 3) & 7;
  const int b = g >> 6;
  const int li = ((b * 8 + h) * 8 + qt) * 8 + s;
  const int t = threadIdx.x;
  const int lane = t & 63;
  const int w = t >> 6;
  const int quad = lane >> 4;
  const int l16 = lane & 15;
  const int x7 = l16 & 7;
  const int q0 = qt << 6;
  const fx4 fzero = {0.f, 0.f, 0.f, 0.f};

  const short* qbase = Qp + (size_t)(b * 512 + q0 + w * 16 + l16) * 1024 + h * 128;
  sx8 aq[4];
#pragma unroll
  for (int kc = 0; kc < 4; kc++) aq[kc] = *(const sx8*)(qbase + kc * 32 + quad * 8);

  fx4 Ot[8];
#pragma unroll
  for (int d = 0; d < 8; d++) Ot[d] = fzero;
  float lsum = 0.f;

  const short* kbase = Kp + (size_t)(b * 8192 + s * 1024) * 1024 + h * 128;
  const short* vbase = Vt + (size_t)(b * 1024 + h * 128) * 8192 + s * 1024;
  const u64* wdp = mb + (size_t)(b * 512 + q0 + w * 16 + l16) * 128 + s * 16;
  const int srow4 = lane >> 4, scb16 = lane & 15;
  const int srow8 = lane >> 3, scb8 = lane & 7;
  const int h4 = ((quad & 1) ^ ((l16 >> 3) & 1)) * 4;

  for (int kt = 0; kt < 16; kt++) {
    __syncthreads();
#pragma unroll
    for (int j = 0; j < 4; j++) {  // K tile
      const int row = (w * 4 + j) * 4 + srow4;
      const int cb = scb16 ^ (row & 7);
      glds16(kbase + (size_t)(kt * 64 + row) * 1024 + cb * 8, &sK[(w * 4 + j) * 512]);
    }
#pragma unroll
    for (int j = 0; j < 4; j++) {  // V^T tile
      const int row = (w * 4 + j) * 8 + srow8;
      const int cb = scb8 ^ (row & 7);
      glds16(vbase + (size_t)row * 8192 + kt * 64 + cb * 8, &sV[(w * 4 + j) * 512]);
    }
    const u64 wd = wdp[kt];
    __syncthreads();
    const unsigned lo = (unsigned)wd, hi = (unsigned)(wd >> 32);
    sx4 pk[4];
#pragma unroll
    for (int nt = 0; nt < 4; nt++) {
      fx4 a = fzero;
      __builtin_amdgcn_s_setprio(1);
#pragma unroll
      for (int kc = 0; kc < 4; kc++) {
        const sx8 kf = *(const sx8*)(&sK[(nt * 16 + l16) * 128 + ((kc * 4 + quad) ^ x7) * 8]);
        a = MFMA32(kf, aq[kc], a);  // S^T: row=key, col=q
      }
      __builtin_amdgcn_s_setprio(0);
      const unsigned bits = (nt & 2) ? hi : lo;
      const int sh = (nt & 1) * 16 + quad * 4;
      float pv[4];
#pragma unroll
      for (int r = 0; r < 4; r++) {
        const float e = __builtin_amdgcn_exp2f(a[r]);  // scale*log2e folded into Qp
        pv[r] = ((bits >> (sh + r)) & 1u) ? e : 0.f;
        lsum += pv[r];
      }
      sx4 pko;
      ((unsigned*)&pko)[0] = __builtin_amdgcn_perm(
          __float_as_uint(pv[1]) + 0x8000u, __float_as_uint(pv[0]) + 0x8000u, 0x07060302u);
      ((unsigned*)&pko)[1] = __builtin_amdgcn_perm(
          __float_as_uint(pv[3]) + 0x8000u, __float_as_uint(pv[2]) + 0x8000u, 0x07060302u);
      pk[nt] = pko;
    }
    __builtin_amdgcn_s_setprio(1);
#pragma unroll
    for (int dt = 0; dt < 8; dt++) {
      fx4 o = Ot[dt];
#pragma unroll
      for (int nt = 0; nt < 4; nt++) {
        const int cb = (2 * nt + (quad >> 1)) ^ x7;
        const sx4 vf = *(const sx4*)(&sV[(dt * 16 + l16) * 64 + cb * 8 + h4]);
        o = MFMA16(vf, pk[nt], o);  // O^T: row=d, col=q
      }
      Ot[dt] = o;
    }
    __builtin_amdgcn_s_setprio(0);
  }
  lsum += __shfl_xor(lsum, 16, 64);
  lsum += __shfl_xor(lsum, 32, 64);
  if (lane < 16) ml[(size_t)li * 64 + w * 16 + l16] = lsum;
  float* ob = Op + (size_t)li * 8192 + (w * 16 + l16) * 128 + quad * 4;
#pragma unroll
  for (int dt = 0; dt < 8; dt++) *(fx4*)(ob + dt * 16) = Ot[dt];
}

// ---------------- combine 8 KL-split partials -> summed bf16 -----------------
__global__ __launch_bounds__(256) void k_combine(const float* __restrict__ ml,
                                                 const float* __restrict__ Op,
                                                 short* __restrict__ summed) {
  const int bx = blockIdx.x;
  const int xc = bx >> 1;
  const int dh = (bx & 1) * 64;
  const int qt = xc & 7;
  const int h = (xc >> 3) & 7;
  const int b = xc >> 6;
  const int t = threadIdx.x;
  const int row = t >> 2;
  const int dg = dh + (t & 3) * 16;
  float L = 0.f;
#pragma unroll
  for (int s = 0; s < 8; s++) L += ml[(size_t)(xc * 8 + s) * 64 + row];
  float o[16];
#pragma unroll
  for (int i = 0; i < 16; i++) o[i] = 0.f;
  if (L != 0.f) {
#pragma unroll
    for (int s = 0; s < 8; s++) {
      const float* src = Op + (size_t)(xc * 8 + s) * 8192 + row * 128 + dg;
#pragma unroll
      for (int i = 0; i < 4; i++) {
        const fx4 v = *(const fx4*)(src + i * 4);
        o[i * 4 + 0] += v[0]; o[i * 4 + 1] += v[1];
        o[i * 4 + 2] += v[2]; o[i * 4 + 3] += v[3];
      }
    }
    const float inv = 1.f / L;
#pragma unroll
    for (int i = 0; i < 16; i++) o[i] *= inv;
  }
  short* dst = summed + (size_t)(b * 512 + qt * 64 + row) * 1024 + h * 128 + dg;
#pragma unroll
  for (int i = 0; i < 2; i++) {
    sx8 pkv;
#pragma unroll
    for (int j = 0; j < 8; j++) pkv[j] = (short)f2bf(o[i * 8 + j]);
    *(sx8*)(dst + i * 8) = pkv;
  }
}

// ---------------- host ------------------------------------------------------
extern "C" void kernel_launch(void* const* d_in, const int* in_sizes, int n_in,
                              void* d_out, int out_size, void* d_ws, size_t ws_size,
                              hipStream_t stream) {
  (void)in_sizes; (void)n_in; (void)out_size; (void)ws_size;
  const float* inq = (const float*)d_in[0];
  const float* ink = (const float*)d_in[1];
  const float* inv = (const float*)d_in[2];
  const int* mask = (const int*)d_in[3];
  const float* Wq = (const float*)d_in[4];
  const float* bq = (const float*)d_in[5];
  const float* Wk = (const float*)d_in[6];
  const float* bk = (const float*)d_in[7];
  const float* Wv = (const float*)d_in[8];
  const float* bv = (const float*)d_in[9];
  const float* Wf = (const float*)d_in[10];
  const float* bf = (const float*)d_in[11];

  char* ws = (char*)d_ws;
  short* Vt = (short*)(ws + 0);            // 33.5MB bf16
  short* Kp = (short*)(ws + 33554432);     // 33.5MB bf16
  float* Op = (float*)(ws + 67108864);     // 33.5MB f32 attn partials
  short* cwq = (short*)(ws + 102760448);   // 2MB each
  short* cwk = (short*)(ws + 104857600);
  short* cwv = (short*)(ws + 106954752);
  short* cwf = (short*)(ws + 109051904);
  short* Qp = (short*)(ws + 111149056);
  short* summed = (short*)(ws + 113246208);
  u64* mb = (u64*)(ws + 115343360);
  float* ml = (float*)(ws + 116391936);

  const float alpha_q = 0.12751757f;  // (1/sqrt(128)) * log2(e)

  k_prep<<<256, 256, 0, stream>>>(Wq, Wk, Wv, Wf, cwq, cwk, cwv, cwf);
  k_proj<<<2576, 512, 0, stream>>>(ink, cwk, bk, Kp, inv, cwv, bv, Vt, inq, cwq,
                                   bq, Qp, alpha_q, mask, mb);
  k_attn<<<1024, 256, 0, stream>>>(Qp, Kp, Vt, mb, ml, Op);
  k_combine<<<256, 256, 0, stream>>>(ml, Op, summed);
  k_gemm_out<<<128, 256, 0, stream>>>(summed, cwf, bf, (float*)d_out);
}